// Round 1
// baseline (965.893 us; speedup 1.0000x reference)
//
#include <hip/hip_runtime.h>
#include <hip/hip_bf16.h>

// SegFormer efficient attention, fp32 baseline.
// B=4 N=4096 C=512 H=8 dh=64 SR=4 -> n_kv=256.
// Pipeline: conv(partials,z-split8) -> reduce+bias+LN -> K,V gemm -> K-transpose
//           -> Q gemm -> fused attention -> out proj.

#define EPSV 1e-5f

// ---------------- generic tiled fp32 GEMM: C[M,N] = A[M,K] @ W[K,N] + bias ----
// BM=64 BN=64 BK=16, 256 threads, 4x4 microtile. LDS padded to 68 floats/row:
// float4-aligned (68*4B=272B, 16B-multiple) and conflict-free on both store+load.
__global__ __launch_bounds__(256)
void gemm_bias(const float* __restrict__ A, const float* __restrict__ W,
               const float* __restrict__ bias, float* __restrict__ Cout,
               int M, int K, int N) {
    __shared__ float As[16][68];
    __shared__ float Bs[16][68];
    const int tid = threadIdx.x;
    const int bm = blockIdx.x * 64;
    const int bn = blockIdx.y * 64;
    const int tm = (tid >> 4) * 4;
    const int tn = (tid & 15) * 4;
    const int ar = tid >> 2;          // 0..63  A-tile row
    const int ac = (tid & 3) * 4;     // 0..12  A-tile col (float4)
    const int br = tid >> 4;          // 0..15  B-tile row
    const int bc = (tid & 15) * 4;    // 0..60  B-tile col (float4)
    float acc[4][4] = {};
    for (int k0 = 0; k0 < K; k0 += 16) {
        const float4 av = *(const float4*)&A[(size_t)(bm + ar) * K + k0 + ac];
        const float4 bv = *(const float4*)&W[(size_t)(k0 + br) * N + bn + bc];
        As[ac + 0][ar] = av.x;
        As[ac + 1][ar] = av.y;
        As[ac + 2][ar] = av.z;
        As[ac + 3][ar] = av.w;
        *(float4*)&Bs[br][bc] = bv;
        __syncthreads();
#pragma unroll
        for (int kk = 0; kk < 16; ++kk) {
            const float4 a4 = *(const float4*)&As[kk][tm];
            const float4 b4 = *(const float4*)&Bs[kk][tn];
            const float a[4] = {a4.x, a4.y, a4.z, a4.w};
            const float b[4] = {b4.x, b4.y, b4.z, b4.w};
#pragma unroll
            for (int i = 0; i < 4; ++i)
#pragma unroll
                for (int j = 0; j < 4; ++j) acc[i][j] += a[i] * b[j];
        }
        __syncthreads();
    }
    const float4 bb = *(const float4*)&bias[bn + tn];
#pragma unroll
    for (int i = 0; i < 4; ++i) {
        float4 o;
        o.x = acc[i][0] + bb.x;
        o.y = acc[i][1] + bb.y;
        o.z = acc[i][2] + bb.z;
        o.w = acc[i][3] + bb.w;
        *(float4*)&Cout[(size_t)(bm + tm + i) * N + bn + tn] = o;
    }
}

// ---------------- SR conv as gathered GEMM, K=8192 split 8 ways (z) ----------
// part[z][p][co], p = b*256 + oh*16 + ow;  A[p][kg] = x[b, (oh*4+i)*64+ow*4+j, ci]
// with kg = ((i*4+j)*512 + ci). w_sr flat [4,4,512,512] == W[kg][co].
__global__ __launch_bounds__(256)
void conv_gemm(const float* __restrict__ x, const float* __restrict__ wsr,
               float* __restrict__ part) {
    __shared__ float As[16][68];
    __shared__ float Bs[16][68];
    const int tid = threadIdx.x;
    const int bm = blockIdx.x * 64;   // rows (1024)
    const int bn = blockIdx.y * 64;   // cols (512)
    const int z  = blockIdx.z;        // K chunk
    const int tm = (tid >> 4) * 4;
    const int tn = (tid & 15) * 4;
    const int ar = tid >> 2;
    const int ac = (tid & 3) * 4;
    const int br = tid >> 4;
    const int bc = (tid & 15) * 4;
    const int p  = bm + ar;
    const int b  = p >> 8;
    const int oh = (p & 255) >> 4;
    const int ow = p & 15;
    float acc[4][4] = {};
    const int kbeg = z * 1024, kend = kbeg + 1024;
    for (int k0 = kbeg; k0 < kend; k0 += 16) {
        const int kg = k0 + ac;            // whole 16-wide tile shares one (i,j)
        const int ci = kg & 511;
        const int ij = kg >> 9;
        const int n  = (oh * 4 + (ij >> 2)) * 64 + ow * 4 + (ij & 3);
        const float4 av = *(const float4*)&x[((size_t)b * 4096 + n) * 512 + ci];
        const float4 bv = *(const float4*)&wsr[(size_t)(k0 + br) * 512 + bn + bc];
        As[ac + 0][ar] = av.x;
        As[ac + 1][ar] = av.y;
        As[ac + 2][ar] = av.z;
        As[ac + 3][ar] = av.w;
        *(float4*)&Bs[br][bc] = bv;
        __syncthreads();
#pragma unroll
        for (int kk = 0; kk < 16; ++kk) {
            const float4 a4 = *(const float4*)&As[kk][tm];
            const float4 b4 = *(const float4*)&Bs[kk][tn];
            const float a[4] = {a4.x, a4.y, a4.z, a4.w};
            const float b[4] = {b4.x, b4.y, b4.z, b4.w};
#pragma unroll
            for (int i = 0; i < 4; ++i)
#pragma unroll
                for (int j = 0; j < 4; ++j) acc[i][j] += a[i] * b[j];
        }
        __syncthreads();
    }
#pragma unroll
    for (int i = 0; i < 4; ++i) {
        float4 o;
        o.x = acc[i][0]; o.y = acc[i][1]; o.z = acc[i][2]; o.w = acc[i][3];
        *(float4*)&part[((size_t)z * 1024 + bm + tm + i) * 512 + bn + tn] = o;
    }
}

// ------------- reduce 8 conv partials + bias, then LayerNorm -> xln ----------
__global__ __launch_bounds__(256)
void reduce_ln(const float* __restrict__ part, const float* __restrict__ bsr,
               const float* __restrict__ gamma, const float* __restrict__ beta,
               float* __restrict__ xln) {
    const int wave = threadIdx.x >> 6;
    const int lane = threadIdx.x & 63;
    const int row = blockIdx.x * 4 + wave;   // 0..1023
    const int c = lane * 8;
    float v[8];
    {
        const float4 a = *(const float4*)&bsr[c];
        const float4 b = *(const float4*)&bsr[c + 4];
        v[0] = a.x; v[1] = a.y; v[2] = a.z; v[3] = a.w;
        v[4] = b.x; v[5] = b.y; v[6] = b.z; v[7] = b.w;
    }
#pragma unroll
    for (int z = 0; z < 8; ++z) {
        const float* pr = &part[((size_t)z * 1024 + row) * 512 + c];
        const float4 a = *(const float4*)pr;
        const float4 b = *(const float4*)(pr + 4);
        v[0] += a.x; v[1] += a.y; v[2] += a.z; v[3] += a.w;
        v[4] += b.x; v[5] += b.y; v[6] += b.z; v[7] += b.w;
    }
    float sum = 0.f;
#pragma unroll
    for (int i = 0; i < 8; ++i) sum += v[i];
#pragma unroll
    for (int off = 32; off >= 1; off >>= 1) sum += __shfl_xor(sum, off);
    const float mu = sum * (1.0f / 512.0f);
    float sq = 0.f;
#pragma unroll
    for (int i = 0; i < 8; ++i) { v[i] -= mu; sq += v[i] * v[i]; }
#pragma unroll
    for (int off = 32; off >= 1; off >>= 1) sq += __shfl_xor(sq, off);
    const float rs = rsqrtf(sq * (1.0f / 512.0f) + EPSV);
    const float4 g1 = *(const float4*)&gamma[c];
    const float4 g2 = *(const float4*)&gamma[c + 4];
    const float4 e1 = *(const float4*)&beta[c];
    const float4 e2 = *(const float4*)&beta[c + 4];
    const float g[8] = {g1.x, g1.y, g1.z, g1.w, g2.x, g2.y, g2.z, g2.w};
    const float e[8] = {e1.x, e1.y, e1.z, e1.w, e2.x, e2.y, e2.z, e2.w};
    float o[8];
#pragma unroll
    for (int i = 0; i < 8; ++i) o[i] = v[i] * rs * g[i] + e[i];
    float4 o1; o1.x = o[0]; o1.y = o[1]; o1.z = o[2]; o1.w = o[3];
    float4 o2; o2.x = o[4]; o2.y = o[5]; o2.z = o[6]; o2.w = o[7];
    *(float4*)&xln[(size_t)row * 512 + c] = o1;
    *(float4*)&xln[(size_t)row * 512 + c + 4] = o2;
}

// ------------- K transpose: ktg[bh][d][j] = kbuf[b*256+j][h*64+d] ------------
__global__ __launch_bounds__(256)
void ktrans(const float* __restrict__ kbuf, float* __restrict__ ktg) {
    const int t = blockIdx.x * 256 + threadIdx.x;   // < 32*64*256
    const int j = t & 255;
    const int d = (t >> 8) & 63;
    const int bh = t >> 14;
    const int b = bh >> 3, h = bh & 7;
    ktg[t] = kbuf[((size_t)(b * 256 + j)) * 512 + h * 64 + d];
}

// ------------- fused attention: scores+softmax+PV per Q-row ------------------
// grid (B*H=32, 64); 4 waves/block, 16 rows/wave. n_kv=256.
// QK: lane owns scores j in [4l,4l+4), reads Ktg[d][0..255] coalesced float4.
// softmax across 4-per-lane x 64 lanes via shfl_xor.
// PV: lane = (k_off = l>>4, d0 = (l&15)*4); p broadcast from LDS; xor-reduce.
__global__ __launch_bounds__(256)
void attn_kernel(const float* __restrict__ Q, const float* __restrict__ Ktg,
                 const float* __restrict__ Vb, float* __restrict__ O) {
    __shared__ float p_sm[4][256];
    const int bh = blockIdx.x;
    const int b = bh >> 3, h = bh & 7;
    const int wave = threadIdx.x >> 6;
    const int lane = threadIdx.x & 63;
    const float* Kt = Ktg + (size_t)bh * 64 * 256;             // [d][j]
    const float* Vh = Vb + (size_t)b * 256 * 512 + h * 64;     // [j][d] stride 512
    const int n0 = blockIdx.y * 64 + wave * 16;
    const int k_off = lane >> 4;
    const int d0 = (lane & 15) << 2;
    for (int r = 0; r < 16; ++r) {
        const int n = n0 + r;
        const float qd = Q[((size_t)b * 4096 + n) * 512 + h * 64 + lane] * 0.125f;
        float s0 = 0.f, s1 = 0.f, s2 = 0.f, s3 = 0.f;
#pragma unroll 8
        for (int d = 0; d < 64; ++d) {
            const float qv = __shfl(qd, d);
            const float4 kv = *(const float4*)&Kt[d * 256 + (lane << 2)];
            s0 += qv * kv.x; s1 += qv * kv.y; s2 += qv * kv.z; s3 += qv * kv.w;
        }
        float m = fmaxf(fmaxf(s0, s1), fmaxf(s2, s3));
#pragma unroll
        for (int off = 32; off >= 1; off >>= 1) m = fmaxf(m, __shfl_xor(m, off));
        const float e0 = __expf(s0 - m), e1 = __expf(s1 - m);
        const float e2 = __expf(s2 - m), e3 = __expf(s3 - m);
        float sum = e0 + e1 + e2 + e3;
#pragma unroll
        for (int off = 32; off >= 1; off >>= 1) sum += __shfl_xor(sum, off);
        const float rinv = 1.0f / sum;
        float4 p4; p4.x = e0 * rinv; p4.y = e1 * rinv; p4.z = e2 * rinv; p4.w = e3 * rinv;
        *(float4*)&p_sm[wave][lane << 2] = p4;
        __syncthreads();
        float4 acc; acc.x = 0.f; acc.y = 0.f; acc.z = 0.f; acc.w = 0.f;
#pragma unroll 8
        for (int kk = 0; kk < 256; kk += 4) {
            const float pk = p_sm[wave][kk + k_off];
            const float4 vv = *(const float4*)&Vh[(size_t)(kk + k_off) * 512 + d0];
            acc.x += pk * vv.x; acc.y += pk * vv.y; acc.z += pk * vv.z; acc.w += pk * vv.w;
        }
        acc.x += __shfl_xor(acc.x, 16); acc.y += __shfl_xor(acc.y, 16);
        acc.z += __shfl_xor(acc.z, 16); acc.w += __shfl_xor(acc.w, 16);
        acc.x += __shfl_xor(acc.x, 32); acc.y += __shfl_xor(acc.y, 32);
        acc.z += __shfl_xor(acc.z, 32); acc.w += __shfl_xor(acc.w, 32);
        if (lane < 16)
            *(float4*)&O[((size_t)b * 4096 + n) * 512 + h * 64 + d0] = acc;
        __syncthreads();
    }
}

extern "C" void kernel_launch(void* const* d_in, const int* in_sizes, int n_in,
                              void* d_out, int out_size, void* d_ws, size_t ws_size,
                              hipStream_t stream) {
    const float* x     = (const float*)d_in[0];
    const float* wq    = (const float*)d_in[1];
    const float* bq    = (const float*)d_in[2];
    const float* wk    = (const float*)d_in[3];
    const float* bk    = (const float*)d_in[4];
    const float* wv    = (const float*)d_in[5];
    const float* bv    = (const float*)d_in[6];
    const float* wsr   = (const float*)d_in[7];
    const float* bsr   = (const float*)d_in[8];
    const float* gamma = (const float*)d_in[9];
    const float* beta  = (const float*)d_in[10];
    const float* wp    = (const float*)d_in[11];
    const float* bp    = (const float*)d_in[12];
    float* out = (float*)d_out;
    float* ws  = (float*)d_ws;

    // workspace layout (floats); conv partials alias attno (dead by attention time)
    float* q_buf = ws;                  // 8,388,608
    float* attno = ws + 8388608;        // 8,388,608
    float* part  = attno;               // 4,194,304 (phase 1-2 only)
    float* xln   = ws + 16777216;       //   524,288
    float* kbuf  = ws + 17301504;       //   524,288
    float* vbuf  = ws + 17825792;       //   524,288
    float* ktg   = ws + 18350080;       //   524,288  (total 75.5 MB)

    conv_gemm<<<dim3(16, 8, 8), 256, 0, stream>>>(x, wsr, part);
    reduce_ln<<<256, 256, 0, stream>>>(part, bsr, gamma, beta, xln);
    gemm_bias<<<dim3(16, 8), 256, 0, stream>>>(xln, wk, bk, kbuf, 1024, 512, 512);
    gemm_bias<<<dim3(16, 8), 256, 0, stream>>>(xln, wv, bv, vbuf, 1024, 512, 512);
    ktrans<<<2048, 256, 0, stream>>>(kbuf, ktg);
    gemm_bias<<<dim3(256, 8), 256, 0, stream>>>(x, wq, bq, q_buf, 16384, 512, 512);
    attn_kernel<<<dim3(32, 64), 256, 0, stream>>>(q_buf, ktg, vbuf, attno);
    gemm_bias<<<dim3(256, 8), 256, 0, stream>>>(attno, wp, bp, out, 16384, 512, 512);
}

// Round 3
// 262.114 us; speedup vs baseline: 3.6850x; 3.6850x over previous
//
#include <hip/hip_runtime.h>
#include <hip/hip_bf16.h>

// SegFormer efficient attention, bf16 MFMA pipeline.
// B=4 N=4096 C=512 H=8 dh=64 SR=4 -> n_kv=256.
// cast/transposes -> conv-GEMM(splitK8,bf16) -> reduce+bias+LN (bf16 out)
//   -> KV GEMM (K normal, V transposed out) -> Q GEMM (scale folded)
//   -> fused attn (swapped QK^T, in-register P) -> out proj (fp32 out).

#define EPSV 1e-5f

typedef __attribute__((ext_vector_type(8))) short short8v;   // 8 bf16 = 1 MFMA operand
typedef __attribute__((ext_vector_type(4))) short short4v;
typedef __attribute__((ext_vector_type(4))) float float4v;

static __device__ __forceinline__ ushort f2bf_bits(float x) {
  union { float f; uint32_t u; } v; v.f = x;
  return (ushort)((v.u + 0x7fffu + ((v.u >> 16) & 1u)) >> 16);   // RNE
}

static __device__ __forceinline__ float4v mfma16(short8v a, short8v b, float4v c) {
  return __builtin_amdgcn_mfma_f32_16x16x32_bf16(a, b, c, 0, 0, 0);
}

// write one staged 16B chunk (8 contiguous-k bf16) into fragment-major LDS.
// lane slot layout: k = 4*(lane>>4) + (j&3) + 16*(j>>2), row-within-frag = lane&15.
static __device__ __forceinline__ void wr_chunk(ushort* lds, int base, int4 v) {
  *(int2*)&lds[base]       = make_int2(v.x, v.y);
  *(int2*)&lds[base + 128] = make_int2(v.z, v.w);
}

// ---------------- casts ----------------
__global__ __launch_bounds__(256) void cast_x(const float* __restrict__ src,
                                              ushort* __restrict__ dst) {
  const int i = blockIdx.x * 256 + threadIdx.x;         // 1,048,576 threads, 8 elems each
  const float4* s4 = (const float4*)src;
  const float4 a = s4[2 * i], b = s4[2 * i + 1];
  short8v v;
  v[0] = (short)f2bf_bits(a.x); v[1] = (short)f2bf_bits(a.y);
  v[2] = (short)f2bf_bits(a.z); v[3] = (short)f2bf_bits(a.w);
  v[4] = (short)f2bf_bits(b.x); v[5] = (short)f2bf_bits(b.y);
  v[6] = (short)f2bf_bits(b.z); v[7] = (short)f2bf_bits(b.w);
  *(short8v*)&dst[(size_t)i * 8] = v;
}

// w [K][512] fp32 -> wT [512][K] bf16 (N fixed at 512)
__global__ __launch_bounds__(256) void tcast(const float* __restrict__ src,
                                             ushort* __restrict__ dst, int K) {
  const int t = blockIdx.x * 256 + threadIdx.x;         // K*128 threads
  const int k = t >> 7, n4 = (t & 127) * 4;
  const float4 v = *(const float4*)&src[(size_t)k * 512 + n4];
  dst[(size_t)(n4 + 0) * K + k] = f2bf_bits(v.x);
  dst[(size_t)(n4 + 1) * K + k] = f2bf_bits(v.y);
  dst[(size_t)(n4 + 2) * K + k] = f2bf_bits(v.z);
  dst[(size_t)(n4 + 3) * K + k] = f2bf_bits(v.w);
}

__global__ __launch_bounds__(256) void concat_bias(const float* __restrict__ bk,
                                                   const float* __restrict__ bv,
                                                   float* __restrict__ bkv) {
  const int i = blockIdx.x * 256 + threadIdx.x;         // 1024
  bkv[i] = (i < 512) ? bk[i] : bv[i - 512];
}

// ---------------- generic bf16 MFMA GEMM ----------------
// C[M,N] = A[M,K] @ BT[N,K]^T (+bias)*scale.  128x128 tile, BK=32, 4 waves (2x2 of 64x64).
// MODE 0: fp32 out; 1: bf16 out; 2: kv-split (col<512 -> K [row][col], col>=512 -> V^T [col-512][row]).
template<int MODE>
__global__ __launch_bounds__(256)
void gemm_bf(const ushort* __restrict__ A, const ushort* __restrict__ BT,
             const float* __restrict__ bias, void* __restrict__ outp,
             int M, int N, int K, float scale) {
  __shared__ ushort lds[8192];                          // A frags [0..4095], B frags [4096..]
  const int tid = threadIdx.x;
  const int wave = tid >> 6, lane = tid & 63;
  const int wm = wave >> 1, wn = wave & 1;
  const int bm = blockIdx.x * 128, bn = blockIdx.y * 128;
  const int lid = lane & 15, lg = lane >> 4;
  const int r0 = tid >> 2, c8 = tid & 3;
  const int g0 = 2 * (c8 & 1), h2 = c8 >> 1;
  const int c0 = c8 * 8;
  const int basew = ((r0 >> 4) * 64 + 16 * g0 + (r0 & 15)) * 8 + h2 * 4;
  float4v acc[4][4];
  const float4v zf = {0.f, 0.f, 0.f, 0.f};
#pragma unroll
  for (int mi = 0; mi < 4; ++mi)
#pragma unroll
    for (int ni = 0; ni < 4; ++ni) acc[mi][ni] = zf;
  const ushort* Ar0 = A + (size_t)(bm + r0) * K;
  const ushort* Ar1 = Ar0 + (size_t)64 * K;
  const ushort* Br0 = BT + (size_t)(bn + r0) * K;
  const ushort* Br1 = Br0 + (size_t)64 * K;
  const int NK = K >> 5;
  int koff = c0;
  int4 pa0 = *(const int4*)(Ar0 + koff), pa1 = *(const int4*)(Ar1 + koff);
  int4 pb0 = *(const int4*)(Br0 + koff), pb1 = *(const int4*)(Br1 + koff);
  for (int kb = 0; kb < NK; ++kb) {
    wr_chunk(lds, basew, pa0);
    wr_chunk(lds, basew + 2048, pa1);
    wr_chunk(lds, basew + 4096, pb0);
    wr_chunk(lds, basew + 6144, pb1);
    __syncthreads();
    if (kb + 1 < NK) {
      koff += 32;
      pa0 = *(const int4*)(Ar0 + koff); pa1 = *(const int4*)(Ar1 + koff);
      pb0 = *(const int4*)(Br0 + koff); pb1 = *(const int4*)(Br1 + koff);
    }
    short8v af[4], bfr[4];
#pragma unroll
    for (int mi = 0; mi < 4; ++mi)
      af[mi] = *(const short8v*)&lds[((wm * 4 + mi) * 64 + lane) * 8];
#pragma unroll
    for (int ni = 0; ni < 4; ++ni)
      bfr[ni] = *(const short8v*)&lds[4096 + ((wn * 4 + ni) * 64 + lane) * 8];
#pragma unroll
    for (int mi = 0; mi < 4; ++mi)
#pragma unroll
      for (int ni = 0; ni < 4; ++ni) acc[mi][ni] = mfma16(af[mi], bfr[ni], acc[mi][ni]);
    __syncthreads();
  }
  float bv[4];
#pragma unroll
  for (int ni = 0; ni < 4; ++ni) bv[ni] = bias[bn + wn * 64 + ni * 16 + lid];
#pragma unroll
  for (int mi = 0; mi < 4; ++mi)
#pragma unroll
    for (int ni = 0; ni < 4; ++ni) {
      const int col = bn + wn * 64 + ni * 16 + lid;
#pragma unroll
      for (int reg = 0; reg < 4; ++reg) {
        const int row = bm + wm * 64 + mi * 16 + 4 * lg + reg;
        const float v = (acc[mi][ni][reg] + bv[ni]) * scale;
        if (MODE == 0) ((float*)outp)[(size_t)row * N + col] = v;
        else if (MODE == 1) ((ushort*)outp)[(size_t)row * N + col] = f2bf_bits(v);
        else {
          if (col < 512) ((ushort*)outp)[(size_t)row * 512 + col] = f2bf_bits(v);
          else ((ushort*)outp)[524288 + (size_t)(col - 512) * 1024 + row] = f2bf_bits(v);
        }
      }
    }
}

// ---------------- conv as gathered GEMM, split-K z=8, fp32 partials ----------------
static __device__ __forceinline__ int4 ld_patch(const ushort* xbf, int b, int oh, int ow, int kg) {
  const int ij = kg >> 9, ci = kg & 511;
  const int n = (oh * 4 + (ij >> 2)) * 64 + ow * 4 + (ij & 3);
  return *(const int4*)(xbf + ((size_t)b * 4096 + n) * 512 + ci);
}

__global__ __launch_bounds__(256)
void conv_bf(const ushort* __restrict__ xbf, const ushort* __restrict__ wsrT,
             float* __restrict__ part) {
  __shared__ ushort lds[8192];
  const int tid = threadIdx.x;
  const int wave = tid >> 6, lane = tid & 63;
  const int wm = wave >> 1, wn = wave & 1;
  const int bm = blockIdx.x * 128, bn = blockIdx.y * 128, z = blockIdx.z;
  const int lid = lane & 15, lg = lane >> 4;
  const int r0 = tid >> 2, c8 = tid & 3;
  const int g0 = 2 * (c8 & 1), h2 = c8 >> 1;
  const int c0 = c8 * 8;
  const int basew = ((r0 >> 4) * 64 + 16 * g0 + (r0 & 15)) * 8 + h2 * 4;
  const int p0 = bm + r0, p1 = p0 + 64;
  const int b0 = p0 >> 8, oh0 = (p0 & 255) >> 4, ow0 = p0 & 15;
  const int b1 = p1 >> 8, oh1 = (p1 & 255) >> 4, ow1 = p1 & 15;
  const ushort* Br0 = wsrT + (size_t)(bn + r0) * 8192;
  const ushort* Br1 = Br0 + (size_t)64 * 8192;
  float4v acc[4][4];
  const float4v zf = {0.f, 0.f, 0.f, 0.f};
#pragma unroll
  for (int mi = 0; mi < 4; ++mi)
#pragma unroll
    for (int ni = 0; ni < 4; ++ni) acc[mi][ni] = zf;
  int kg = z * 1024 + c0;
  int4 pa0 = ld_patch(xbf, b0, oh0, ow0, kg);
  int4 pa1 = ld_patch(xbf, b1, oh1, ow1, kg);
  int4 pb0 = *(const int4*)(Br0 + kg);
  int4 pb1 = *(const int4*)(Br1 + kg);
  for (int kb = 0; kb < 32; ++kb) {
    wr_chunk(lds, basew, pa0);
    wr_chunk(lds, basew + 2048, pa1);
    wr_chunk(lds, basew + 4096, pb0);
    wr_chunk(lds, basew + 6144, pb1);
    __syncthreads();
    if (kb < 31) {
      kg += 32;
      pa0 = ld_patch(xbf, b0, oh0, ow0, kg);
      pa1 = ld_patch(xbf, b1, oh1, ow1, kg);
      pb0 = *(const int4*)(Br0 + kg);
      pb1 = *(const int4*)(Br1 + kg);
    }
    short8v af[4], bfr[4];
#pragma unroll
    for (int mi = 0; mi < 4; ++mi)
      af[mi] = *(const short8v*)&lds[((wm * 4 + mi) * 64 + lane) * 8];
#pragma unroll
    for (int ni = 0; ni < 4; ++ni)
      bfr[ni] = *(const short8v*)&lds[4096 + ((wn * 4 + ni) * 64 + lane) * 8];
#pragma unroll
    for (int mi = 0; mi < 4; ++mi)
#pragma unroll
      for (int ni = 0; ni < 4; ++ni) acc[mi][ni] = mfma16(af[mi], bfr[ni], acc[mi][ni]);
    __syncthreads();
  }
#pragma unroll
  for (int mi = 0; mi < 4; ++mi)
#pragma unroll
    for (int ni = 0; ni < 4; ++ni)
#pragma unroll
      for (int reg = 0; reg < 4; ++reg)
        part[(size_t)(z * 1024 + bm + wm * 64 + mi * 16 + 4 * lg + reg) * 512 +
             bn + wn * 64 + ni * 16 + lid] = acc[mi][ni][reg];
}

// ---------------- reduce conv partials + bias, LayerNorm -> bf16 ----------------
__global__ __launch_bounds__(256)
void reduce_ln(const float* __restrict__ part, const float* __restrict__ bsr,
               const float* __restrict__ gamma, const float* __restrict__ beta,
               ushort* __restrict__ xln) {
  const int wave = threadIdx.x >> 6;
  const int lane = threadIdx.x & 63;
  const int row = blockIdx.x * 4 + wave;
  const int c = lane * 8;
  float v[8];
  {
    const float4 a = *(const float4*)&bsr[c];
    const float4 b = *(const float4*)&bsr[c + 4];
    v[0] = a.x; v[1] = a.y; v[2] = a.z; v[3] = a.w;
    v[4] = b.x; v[5] = b.y; v[6] = b.z; v[7] = b.w;
  }
#pragma unroll
  for (int z = 0; z < 8; ++z) {
    const float* pr = &part[((size_t)z * 1024 + row) * 512 + c];
    const float4 a = *(const float4*)pr;
    const float4 b = *(const float4*)(pr + 4);
    v[0] += a.x; v[1] += a.y; v[2] += a.z; v[3] += a.w;
    v[4] += b.x; v[5] += b.y; v[6] += b.z; v[7] += b.w;
  }
  float sum = 0.f;
#pragma unroll
  for (int i = 0; i < 8; ++i) sum += v[i];
#pragma unroll
  for (int off = 32; off >= 1; off >>= 1) sum += __shfl_xor(sum, off);
  const float mu = sum * (1.0f / 512.0f);
  float sq = 0.f;
#pragma unroll
  for (int i = 0; i < 8; ++i) { v[i] -= mu; sq += v[i] * v[i]; }
#pragma unroll
  for (int off = 32; off >= 1; off >>= 1) sq += __shfl_xor(sq, off);
  const float rs = rsqrtf(sq * (1.0f / 512.0f) + EPSV);
  const float4 g1 = *(const float4*)&gamma[c];
  const float4 g2 = *(const float4*)&gamma[c + 4];
  const float4 e1 = *(const float4*)&beta[c];
  const float4 e2 = *(const float4*)&beta[c + 4];
  const float g[8] = {g1.x, g1.y, g1.z, g1.w, g2.x, g2.y, g2.z, g2.w};
  const float e[8] = {e1.x, e1.y, e1.z, e1.w, e2.x, e2.y, e2.z, e2.w};
  short8v ov;
#pragma unroll
  for (int i = 0; i < 8; ++i) ov[i] = (short)f2bf_bits(v[i] * rs * g[i] + e[i]);
  *(short8v*)&xln[(size_t)row * 512 + c] = ov;
}

// ---------------- fused attention ----------------
// grid (32 bh, 32 qtiles). block = 4 waves, each wave: 32 q x 256 kv.
// S^T = mfma(K, Q^T-frags): lane holds S[q=lid+16qf][kv=16kvf+4lg+reg] -> in-reg softmax
// -> P stays lane-local as PV's A operand (layout identity). V^T staged frag-major for B.
__global__ __launch_bounds__(256)
void attn_bf(const ushort* __restrict__ qbf, const ushort* __restrict__ kbf,
             const ushort* __restrict__ vt, ushort* __restrict__ attno) {
  __shared__ ushort kv_lds[16384];                      // 32KB: K frags, then V frags
  const int bh = blockIdx.x, qt = blockIdx.y;
  const int b = bh >> 3, h = bh & 7;
  const int tid = threadIdx.x;
  const int wave = tid >> 6, lane = tid & 63;
  const int lid = lane & 15, lg = lane >> 4;
  // ---- stage K (256 kv x 64 d), fragment-major ----
  {
    const ushort* Kb = kbf + (size_t)(b * 256) * 512 + h * 64;
#pragma unroll
    for (int i = 0; i < 8; ++i) {
      const int u = i * 256 + tid;
      const int kv = u >> 3, c8 = u & 7, d0 = c8 * 8;
      const int4 d = *(const int4*)(Kb + (size_t)kv * 512 + d0);
      const int f = (kv >> 4) * 2 + (d0 >> 5);
      const int g0 = (d0 >> 2) & 3, hh2 = (d0 >> 4) & 1;
      wr_chunk(kv_lds, (f * 64 + 16 * g0 + (kv & 15)) * 8 + hh2 * 4, d);
    }
  }
  // ---- Q fragments to registers ----
  short8v qfr[2][2];
  const int qrow0 = qt * 128 + wave * 32;
#pragma unroll
  for (int qf = 0; qf < 2; ++qf)
#pragma unroll
    for (int t = 0; t < 2; ++t) {
      const size_t base = (size_t)(b * 4096 + qrow0 + qf * 16 + lid) * 512 + h * 64 + 32 * t + 4 * lg;
      const short4v lo = *(const short4v*)&qbf[base];
      const short4v hi = *(const short4v*)&qbf[base + 16];
      short8v q;
      q[0] = lo[0]; q[1] = lo[1]; q[2] = lo[2]; q[3] = lo[3];
      q[4] = hi[0]; q[5] = hi[1]; q[6] = hi[2]; q[7] = hi[3];
      qfr[qf][t] = q;
    }
  __syncthreads();
  // ---- QK^T (S^T in acc) ----
  float4v s[16][2];
  const float4v zf = {0.f, 0.f, 0.f, 0.f};
#pragma unroll
  for (int kvf = 0; kvf < 16; ++kvf) { s[kvf][0] = zf; s[kvf][1] = zf; }
#pragma unroll
  for (int kvf = 0; kvf < 16; ++kvf)
#pragma unroll
    for (int t = 0; t < 2; ++t) {
      const short8v ka = *(const short8v*)&kv_lds[((kvf * 2 + t) * 64 + lane) * 8];
      s[kvf][0] = mfma16(ka, qfr[0][t], s[kvf][0]);
      s[kvf][1] = mfma16(ka, qfr[1][t], s[kvf][1]);
    }
  // ---- softmax over kv (rows of S^T) ----
  float inv[2];
#pragma unroll
  for (int qf = 0; qf < 2; ++qf) {
    float m = -1e30f;
#pragma unroll
    for (int kvf = 0; kvf < 16; ++kvf)
#pragma unroll
      for (int e = 0; e < 4; ++e) m = fmaxf(m, s[kvf][qf][e]);
    m = fmaxf(m, __shfl_xor(m, 16));
    m = fmaxf(m, __shfl_xor(m, 32));
    float sum = 0.f;
#pragma unroll
    for (int kvf = 0; kvf < 16; ++kvf)
#pragma unroll
      for (int e = 0; e < 4; ++e) {
        const float p = __expf(s[kvf][qf][e] - m);
        s[kvf][qf][e] = p;
        sum += p;
      }
    sum += __shfl_xor(sum, 16);
    sum += __shfl_xor(sum, 32);
    inv[qf] = 1.0f / sum;
  }
  // ---- stage V^T (64 d x 256 kv), fragment-major ----
  __syncthreads();
  {
    const ushort* Vb = vt + (size_t)(h * 64) * 1024 + b * 256;
#pragma unroll
    for (int i = 0; i < 8; ++i) {
      const int u = i * 256 + tid;
      const int d = u >> 5, c8 = u & 31, kv0 = c8 * 8;
      const int4 dd = *(const int4*)(Vb + (size_t)d * 1024 + kv0);
      const int f = (d >> 4) * 8 + (kv0 >> 5);
      const int g0 = (kv0 >> 2) & 3, hh2 = (kv0 >> 4) & 1;
      wr_chunk(kv_lds, (f * 64 + 16 * g0 + (d & 15)) * 8 + hh2 * 4, dd);
    }
  }
  __syncthreads();
  // ---- PV ----
  float4v o[2][4];
#pragma unroll
  for (int qf = 0; qf < 2; ++qf)
#pragma unroll
    for (int nf = 0; nf < 4; ++nf) o[qf][nf] = zf;
#pragma unroll
  for (int t = 0; t < 8; ++t) {
    short8v vb[4];
#pragma unroll
    for (int nf = 0; nf < 4; ++nf)
      vb[nf] = *(const short8v*)&kv_lds[((nf * 8 + t) * 64 + lane) * 8];
#pragma unroll
    for (int qf = 0; qf < 2; ++qf) {
      short8v pa;
#pragma unroll
      for (int j = 0; j < 4; ++j) {
        pa[j]     = (short)f2bf_bits(s[2 * t][qf][j] * inv[qf]);
        pa[4 + j] = (short)f2bf_bits(s[2 * t + 1][qf][j] * inv[qf]);
      }
#pragma unroll
      for (int nf = 0; nf < 4; ++nf) o[qf][nf] = mfma16(pa, vb[nf], o[qf][nf]);
    }
  }
  // ---- store ----
#pragma unroll
  for (int qf = 0; qf < 2; ++qf)
#pragma unroll
    for (int nf = 0; nf < 4; ++nf)
#pragma unroll
      for (int reg = 0; reg < 4; ++reg) {
        const int q = qrow0 + qf * 16 + 4 * lg + reg;
        const int c = h * 64 + nf * 16 + lid;
        attno[(size_t)(b * 4096 + q) * 512 + c] = f2bf_bits(o[qf][nf][reg]);
      }
}

extern "C" void kernel_launch(void* const* d_in, const int* in_sizes, int n_in,
                              void* d_out, int out_size, void* d_ws, size_t ws_size,
                              hipStream_t stream) {
  const float* x     = (const float*)d_in[0];
  const float* wq    = (const float*)d_in[1];
  const float* bq    = (const float*)d_in[2];
  const float* wk    = (const float*)d_in[3];
  const float* bk    = (const float*)d_in[4];
  const float* wv    = (const float*)d_in[5];
  const float* bv    = (const float*)d_in[6];
  const float* wsr   = (const float*)d_in[7];
  const float* bsr   = (const float*)d_in[8];
  const float* gamma = (const float*)d_in[9];
  const float* beta  = (const float*)d_in[10];
  const float* wp    = (const float*)d_in[11];
  const float* bp    = (const float*)d_in[12];
  float* out = (float*)d_out;

  char* w = (char*)d_ws;
  ushort* xbf   = (ushort*)(w);                 // 16,777,216 B
  ushort* qbf   = (ushort*)(w + 16777216);      // 16,777,216
  ushort* attno = (ushort*)(w + 33554432);      // 16,777,216 (aliases part)
  float*  part  = (float*) (w + 33554432);      // 16,777,216 (conv partials, early)
  ushort* wsrT  = (ushort*)(w + 50331648);      //  8,388,608
  ushort* wqT   = (ushort*)(w + 58720256);      //    524,288
  ushort* wpT   = (ushort*)(w + 59244544);      //    524,288
  ushort* wkvT  = (ushort*)(w + 59768832);      //  1,048,576
  ushort* xln   = (ushort*)(w + 60817408);      //  1,048,576
  ushort* kbf   = (ushort*)(w + 61865984);      //  1,048,576 (K)
  ushort* vt    = (ushort*)(w + 62914560);      //  1,048,576 (V^T), contiguous after kbf
  float*  bkv   = (float*) (w + 63963136);      //      4,096

  cast_x<<<4096, 256, 0, stream>>>(x, xbf);
  tcast<<<256, 256, 0, stream>>>(wq, wqT, 512);
  tcast<<<256, 256, 0, stream>>>(wk, wkvT, 512);
  tcast<<<256, 256, 0, stream>>>(wv, wkvT + 512 * 512, 512);
  tcast<<<256, 256, 0, stream>>>(wp, wpT, 512);
  tcast<<<4096, 256, 0, stream>>>(wsr, wsrT, 8192);
  concat_bias<<<4, 256, 0, stream>>>(bk, bv, bkv);

  conv_bf<<<dim3(8, 4, 8), 256, 0, stream>>>(xbf, wsrT, part);
  reduce_ln<<<256, 256, 0, stream>>>(part, bsr, gamma, beta, xln);
  gemm_bf<2><<<dim3(8, 8), 256, 0, stream>>>(xln, wkvT, bkv, kbf, 1024, 1024, 512, 1.0f);
  gemm_bf<1><<<dim3(128, 4), 256, 0, stream>>>(xbf, wqT, bq, qbf, 16384, 512, 512, 0.125f);
  attn_bf<<<dim3(32, 32), 256, 0, stream>>>(qbf, kbf, vt, attno);
  gemm_bf<0><<<dim3(128, 4), 256, 0, stream>>>(attno, wpT, bp, out, 16384, 512, 512, 1.0f);
}

// Round 4
// 241.099 us; speedup vs baseline: 4.0062x; 1.0872x over previous
//
#include <hip/hip_runtime.h>
#include <hip/hip_bf16.h>

// SegFormer efficient attention, bf16 MFMA pipeline, round 4.
// B=4 N=4096 C=512 H=8 dh=64 SR=4 -> n_kv=256.
// prep(all casts/transposes, 1 launch) -> conv-GEMM(splitK16) -> reduce+LN
//   -> KV GEMM (K normal, V^T out) -> Q GEMM (0.125*log2e folded)
//   -> fused attn (swapped QK^T, exp2, deferred 1/sum) -> out proj (fp32).

#define EPSV 1e-5f
#define SCALE_Q 0.18033688011112042f   // 0.125 * log2(e)

typedef __attribute__((ext_vector_type(8))) short short8v;   // 8 bf16 = 1 MFMA operand
typedef __attribute__((ext_vector_type(4))) short short4v;
typedef __attribute__((ext_vector_type(4))) float float4v;

static __device__ __forceinline__ ushort f2bf_bits(float x) {
  __hip_bfloat16 h = __float2bfloat16(x);            // RNE; compiler can fuse cvt_pk
  return *(ushort*)&h;
}

static __device__ __forceinline__ float4v mfma16(short8v a, short8v b, float4v c) {
  return __builtin_amdgcn_mfma_f32_16x16x32_bf16(a, b, c, 0, 0, 0);
}

// write one staged 16B chunk (8 contiguous-k bf16) into fragment-major LDS.
// lane slot layout: k = 4*(lane>>4) + (j&3) + 16*(j>>2), row-within-frag = lane&15.
static __device__ __forceinline__ void wr_chunk(ushort* lds, int base, int4 v) {
  *(int2*)&lds[base]       = make_int2(v.x, v.y);
  *(int2*)&lds[base + 128] = make_int2(v.z, v.w);
}

// ---------------- prep: all casts/transposes/bias in one launch ----------------
// blocks [0,4096): cast x -> xbf            (8 elems/thread)
// blocks [4096,8192): wsr [8192][512] -> wsrT [512][8192]
// blocks [8192,9216): wq/wk/wv/wp [512][512] -> T  (256 blocks each)
// blocks [9216,9220): bkv concat
__global__ __launch_bounds__(256)
void prep(const float* __restrict__ x, const float* __restrict__ wq,
          const float* __restrict__ wk, const float* __restrict__ wv,
          const float* __restrict__ wp, const float* __restrict__ wsr,
          const float* __restrict__ bk, const float* __restrict__ bv,
          ushort* __restrict__ xbf, ushort* __restrict__ wqT,
          ushort* __restrict__ wkvT, ushort* __restrict__ wpT,
          ushort* __restrict__ wsrT, float* __restrict__ bkv) {
  const int bid = blockIdx.x, tid = threadIdx.x;
  if (bid < 4096) {
    const int i = bid * 256 + tid;
    const float4* s4 = (const float4*)x;
    const float4 a = s4[2 * i], b = s4[2 * i + 1];
    short8v v;
    v[0] = (short)f2bf_bits(a.x); v[1] = (short)f2bf_bits(a.y);
    v[2] = (short)f2bf_bits(a.z); v[3] = (short)f2bf_bits(a.w);
    v[4] = (short)f2bf_bits(b.x); v[5] = (short)f2bf_bits(b.y);
    v[6] = (short)f2bf_bits(b.z); v[7] = (short)f2bf_bits(b.w);
    *(short8v*)&xbf[(size_t)i * 8] = v;
  } else if (bid < 8192) {
    const int t = (bid - 4096) * 256 + tid;            // < 1,048,576
    const int k = t >> 7, n4 = (t & 127) * 4;
    const float4 v = *(const float4*)&wsr[(size_t)k * 512 + n4];
    wsrT[(size_t)(n4 + 0) * 8192 + k] = f2bf_bits(v.x);
    wsrT[(size_t)(n4 + 1) * 8192 + k] = f2bf_bits(v.y);
    wsrT[(size_t)(n4 + 2) * 8192 + k] = f2bf_bits(v.z);
    wsrT[(size_t)(n4 + 3) * 8192 + k] = f2bf_bits(v.w);
  } else if (bid < 9216) {
    const int wsel = (bid - 8192) >> 8;
    const int t = ((bid - 8192) & 255) * 256 + tid;    // < 65,536
    const float* src = wsel == 0 ? wq : wsel == 1 ? wk : wsel == 2 ? wv : wp;
    ushort* dst = wsel == 0 ? wqT : wsel == 1 ? wkvT : wsel == 2 ? (wkvT + 262144) : wpT;
    const int k = t >> 7, n4 = (t & 127) * 4;
    const float4 v = *(const float4*)&src[(size_t)k * 512 + n4];
    dst[(size_t)(n4 + 0) * 512 + k] = f2bf_bits(v.x);
    dst[(size_t)(n4 + 1) * 512 + k] = f2bf_bits(v.y);
    dst[(size_t)(n4 + 2) * 512 + k] = f2bf_bits(v.z);
    dst[(size_t)(n4 + 3) * 512 + k] = f2bf_bits(v.w);
  } else {
    const int i = (bid - 9216) * 256 + tid;            // < 1024
    bkv[i] = (i < 512) ? bk[i] : bv[i - 512];
  }
}

// ---------------- generic bf16 MFMA GEMM ----------------
// C[M,N] = A[M,K] @ BT[N,K]^T (+bias)*scale.  128x128 tile, BK=32, 4 waves (2x2 of 64x64).
// MODE 0: fp32 out; 1: bf16 out; 2: kv-split (col<512 -> K [row][col], col>=512 -> V^T [col-512][row]).
template<int MODE>
__global__ __launch_bounds__(256)
void gemm_bf(const ushort* __restrict__ A, const ushort* __restrict__ BT,
             const float* __restrict__ bias, void* __restrict__ outp,
             int M, int N, int K, float scale) {
  __shared__ ushort lds[8192];                          // A frags [0..4095], B frags [4096..]
  const int tid = threadIdx.x;
  const int wave = tid >> 6, lane = tid & 63;
  const int wm = wave >> 1, wn = wave & 1;
  const int bm = blockIdx.x * 128, bn = blockIdx.y * 128;
  const int lid = lane & 15, lg = lane >> 4;
  const int r0 = tid >> 2, c8 = tid & 3;
  const int g0 = 2 * (c8 & 1), h2 = c8 >> 1;
  const int c0 = c8 * 8;
  const int basew = ((r0 >> 4) * 64 + 16 * g0 + (r0 & 15)) * 8 + h2 * 4;
  float4v acc[4][4];
  const float4v zf = {0.f, 0.f, 0.f, 0.f};
#pragma unroll
  for (int mi = 0; mi < 4; ++mi)
#pragma unroll
    for (int ni = 0; ni < 4; ++ni) acc[mi][ni] = zf;
  const ushort* Ar0 = A + (size_t)(bm + r0) * K;
  const ushort* Ar1 = Ar0 + (size_t)64 * K;
  const ushort* Br0 = BT + (size_t)(bn + r0) * K;
  const ushort* Br1 = Br0 + (size_t)64 * K;
  const int NK = K >> 5;
  int koff = c0;
  int4 pa0 = *(const int4*)(Ar0 + koff), pa1 = *(const int4*)(Ar1 + koff);
  int4 pb0 = *(const int4*)(Br0 + koff), pb1 = *(const int4*)(Br1 + koff);
  for (int kb = 0; kb < NK; ++kb) {
    wr_chunk(lds, basew, pa0);
    wr_chunk(lds, basew + 2048, pa1);
    wr_chunk(lds, basew + 4096, pb0);
    wr_chunk(lds, basew + 6144, pb1);
    __syncthreads();
    if (kb + 1 < NK) {
      koff += 32;
      pa0 = *(const int4*)(Ar0 + koff); pa1 = *(const int4*)(Ar1 + koff);
      pb0 = *(const int4*)(Br0 + koff); pb1 = *(const int4*)(Br1 + koff);
    }
    short8v af[4], bfr[4];
#pragma unroll
    for (int mi = 0; mi < 4; ++mi)
      af[mi] = *(const short8v*)&lds[((wm * 4 + mi) * 64 + lane) * 8];
#pragma unroll
    for (int ni = 0; ni < 4; ++ni)
      bfr[ni] = *(const short8v*)&lds[4096 + ((wn * 4 + ni) * 64 + lane) * 8];
#pragma unroll
    for (int mi = 0; mi < 4; ++mi)
#pragma unroll
      for (int ni = 0; ni < 4; ++ni) acc[mi][ni] = mfma16(af[mi], bfr[ni], acc[mi][ni]);
    __syncthreads();
  }
  float bvv[4];
#pragma unroll
  for (int ni = 0; ni < 4; ++ni) bvv[ni] = bias[bn + wn * 64 + ni * 16 + lid];
#pragma unroll
  for (int mi = 0; mi < 4; ++mi)
#pragma unroll
    for (int ni = 0; ni < 4; ++ni) {
      const int col = bn + wn * 64 + ni * 16 + lid;
#pragma unroll
      for (int reg = 0; reg < 4; ++reg) {
        const int row = bm + wm * 64 + mi * 16 + 4 * lg + reg;
        const float v = (acc[mi][ni][reg] + bvv[ni]) * scale;
        if (MODE == 0) ((float*)outp)[(size_t)row * N + col] = v;
        else if (MODE == 1) ((ushort*)outp)[(size_t)row * N + col] = f2bf_bits(v);
        else {
          if (col < 512) ((ushort*)outp)[(size_t)row * 512 + col] = f2bf_bits(v);
          else ((ushort*)outp)[524288 + (size_t)(col - 512) * 1024 + row] = f2bf_bits(v);
        }
      }
    }
}

// ---------------- conv as gathered GEMM, split-K z=16, fp32 partials ----------------
static __device__ __forceinline__ int4 ld_patch(const ushort* xbf, int b, int oh, int ow, int kg) {
  const int ij = kg >> 9, ci = kg & 511;
  const int n = (oh * 4 + (ij >> 2)) * 64 + ow * 4 + (ij & 3);
  return *(const int4*)(xbf + ((size_t)b * 4096 + n) * 512 + ci);
}

__global__ __launch_bounds__(256)
void conv_bf(const ushort* __restrict__ xbf, const ushort* __restrict__ wsrT,
             float* __restrict__ part) {
  __shared__ ushort lds[8192];
  const int tid = threadIdx.x;
  const int wave = tid >> 6, lane = tid & 63;
  const int wm = wave >> 1, wn = wave & 1;
  const int bm = blockIdx.x * 128, bn = blockIdx.y * 128, z = blockIdx.z;
  const int lid = lane & 15, lg = lane >> 4;
  const int r0 = tid >> 2, c8 = tid & 3;
  const int g0 = 2 * (c8 & 1), h2 = c8 >> 1;
  const int c0 = c8 * 8;
  const int basew = ((r0 >> 4) * 64 + 16 * g0 + (r0 & 15)) * 8 + h2 * 4;
  const int p0 = bm + r0, p1 = p0 + 64;
  const int b0 = p0 >> 8, oh0 = (p0 & 255) >> 4, ow0 = p0 & 15;
  const int b1 = p1 >> 8, oh1 = (p1 & 255) >> 4, ow1 = p1 & 15;
  const ushort* Br0 = wsrT + (size_t)(bn + r0) * 8192;
  const ushort* Br1 = Br0 + (size_t)64 * 8192;
  float4v acc[4][4];
  const float4v zf = {0.f, 0.f, 0.f, 0.f};
#pragma unroll
  for (int mi = 0; mi < 4; ++mi)
#pragma unroll
    for (int ni = 0; ni < 4; ++ni) acc[mi][ni] = zf;
  int kg = z * 512 + c0;
  int4 pa0 = ld_patch(xbf, b0, oh0, ow0, kg);
  int4 pa1 = ld_patch(xbf, b1, oh1, ow1, kg);
  int4 pb0 = *(const int4*)(Br0 + kg);
  int4 pb1 = *(const int4*)(Br1 + kg);
  for (int kb = 0; kb < 16; ++kb) {
    wr_chunk(lds, basew, pa0);
    wr_chunk(lds, basew + 2048, pa1);
    wr_chunk(lds, basew + 4096, pb0);
    wr_chunk(lds, basew + 6144, pb1);
    __syncthreads();
    if (kb < 15) {
      kg += 32;
      pa0 = ld_patch(xbf, b0, oh0, ow0, kg);
      pa1 = ld_patch(xbf, b1, oh1, ow1, kg);
      pb0 = *(const int4*)(Br0 + kg);
      pb1 = *(const int4*)(Br1 + kg);
    }
    short8v af[4], bfr[4];
#pragma unroll
    for (int mi = 0; mi < 4; ++mi)
      af[mi] = *(const short8v*)&lds[((wm * 4 + mi) * 64 + lane) * 8];
#pragma unroll
    for (int ni = 0; ni < 4; ++ni)
      bfr[ni] = *(const short8v*)&lds[4096 + ((wn * 4 + ni) * 64 + lane) * 8];
#pragma unroll
    for (int mi = 0; mi < 4; ++mi)
#pragma unroll
      for (int ni = 0; ni < 4; ++ni) acc[mi][ni] = mfma16(af[mi], bfr[ni], acc[mi][ni]);
    __syncthreads();
  }
#pragma unroll
  for (int mi = 0; mi < 4; ++mi)
#pragma unroll
    for (int ni = 0; ni < 4; ++ni)
#pragma unroll
      for (int reg = 0; reg < 4; ++reg)
        part[(size_t)(z * 1024 + bm + wm * 64 + mi * 16 + 4 * lg + reg) * 512 +
             bn + wn * 64 + ni * 16 + lid] = acc[mi][ni][reg];
}

// ---------------- reduce conv partials + bias, LayerNorm -> bf16 ----------------
__global__ __launch_bounds__(256)
void reduce_ln(const float* __restrict__ part, const float* __restrict__ bsr,
               const float* __restrict__ gamma, const float* __restrict__ beta,
               ushort* __restrict__ xln) {
  const int wave = threadIdx.x >> 6;
  const int lane = threadIdx.x & 63;
  const int row = blockIdx.x * 4 + wave;
  const int c = lane * 8;
  float v[8];
  {
    const float4 a = *(const float4*)&bsr[c];
    const float4 b = *(const float4*)&bsr[c + 4];
    v[0] = a.x; v[1] = a.y; v[2] = a.z; v[3] = a.w;
    v[4] = b.x; v[5] = b.y; v[6] = b.z; v[7] = b.w;
  }
#pragma unroll
  for (int z = 0; z < 16; ++z) {
    const float* pr = &part[((size_t)z * 1024 + row) * 512 + c];
    const float4 a = *(const float4*)pr;
    const float4 b = *(const float4*)(pr + 4);
    v[0] += a.x; v[1] += a.y; v[2] += a.z; v[3] += a.w;
    v[4] += b.x; v[5] += b.y; v[6] += b.z; v[7] += b.w;
  }
  float sum = 0.f;
#pragma unroll
  for (int i = 0; i < 8; ++i) sum += v[i];
#pragma unroll
  for (int off = 32; off >= 1; off >>= 1) sum += __shfl_xor(sum, off);
  const float mu = sum * (1.0f / 512.0f);
  float sq = 0.f;
#pragma unroll
  for (int i = 0; i < 8; ++i) { v[i] -= mu; sq += v[i] * v[i]; }
#pragma unroll
  for (int off = 32; off >= 1; off >>= 1) sq += __shfl_xor(sq, off);
  const float rs = rsqrtf(sq * (1.0f / 512.0f) + EPSV);
  const float4 g1 = *(const float4*)&gamma[c];
  const float4 g2 = *(const float4*)&gamma[c + 4];
  const float4 e1 = *(const float4*)&beta[c];
  const float4 e2 = *(const float4*)&beta[c + 4];
  const float g[8] = {g1.x, g1.y, g1.z, g1.w, g2.x, g2.y, g2.z, g2.w};
  const float e[8] = {e1.x, e1.y, e1.z, e1.w, e2.x, e2.y, e2.z, e2.w};
  short8v ov;
#pragma unroll
  for (int i = 0; i < 8; ++i) ov[i] = (short)f2bf_bits(v[i] * rs * g[i] + e[i]);
  *(short8v*)&xln[(size_t)row * 512 + c] = ov;
}

// ---------------- fused attention ----------------
// grid (32 bh, 32 qtiles). block = 4 waves, each wave: 32 q x 256 kv.
// S^T = mfma(K, Q^T-frags): lane holds S[q=lid+16qf][kv=16kvf+4lg+reg] -> in-reg softmax
// (exp2; 1/sum deferred to output). P lane-local as PV's A operand. V^T staged frag-major.
__global__ __launch_bounds__(256)
void attn_bf(const ushort* __restrict__ qbf, const ushort* __restrict__ kbf,
             const ushort* __restrict__ vt, ushort* __restrict__ attno) {
  __shared__ ushort kv_lds[16384];                      // 32KB: K frags, then V frags
  const int bh = blockIdx.x, qt = blockIdx.y;
  const int b = bh >> 3, h = bh & 7;
  const int tid = threadIdx.x;
  const int wave = tid >> 6, lane = tid & 63;
  const int lid = lane & 15, lg = lane >> 4;
  // ---- stage K (256 kv x 64 d), fragment-major ----
  {
    const ushort* Kb = kbf + (size_t)(b * 256) * 512 + h * 64;
#pragma unroll
    for (int i = 0; i < 8; ++i) {
      const int u = i * 256 + tid;
      const int kv = u >> 3, c8 = u & 7, d0 = c8 * 8;
      const int4 d = *(const int4*)(Kb + (size_t)kv * 512 + d0);
      const int f = (kv >> 4) * 2 + (d0 >> 5);
      const int g0 = (d0 >> 2) & 3, hh2 = (d0 >> 4) & 1;
      wr_chunk(kv_lds, (f * 64 + 16 * g0 + (kv & 15)) * 8 + hh2 * 4, d);
    }
  }
  // ---- Q fragments to registers ----
  short8v qfr[2][2];
  const int qrow0 = qt * 128 + wave * 32;
#pragma unroll
  for (int qf = 0; qf < 2; ++qf)
#pragma unroll
    for (int t = 0; t < 2; ++t) {
      const size_t base = (size_t)(b * 4096 + qrow0 + qf * 16 + lid) * 512 + h * 64 + 32 * t + 4 * lg;
      const short4v lo = *(const short4v*)&qbf[base];
      const short4v hi = *(const short4v*)&qbf[base + 16];
      short8v q;
      q[0] = lo[0]; q[1] = lo[1]; q[2] = lo[2]; q[3] = lo[3];
      q[4] = hi[0]; q[5] = hi[1]; q[6] = hi[2]; q[7] = hi[3];
      qfr[qf][t] = q;
    }
  __syncthreads();
  // ---- QK^T (S^T in acc) ----
  float4v s[16][2];
  const float4v zf = {0.f, 0.f, 0.f, 0.f};
#pragma unroll
  for (int kvf = 0; kvf < 16; ++kvf) { s[kvf][0] = zf; s[kvf][1] = zf; }
#pragma unroll
  for (int kvf = 0; kvf < 16; ++kvf)
#pragma unroll
    for (int t = 0; t < 2; ++t) {
      const short8v ka = *(const short8v*)&kv_lds[((kvf * 2 + t) * 64 + lane) * 8];
      s[kvf][0] = mfma16(ka, qfr[0][t], s[kvf][0]);
      s[kvf][1] = mfma16(ka, qfr[1][t], s[kvf][1]);
    }
  // ---- softmax over kv (rows of S^T); scores are pre-scaled by log2e ----
  float inv[2];
#pragma unroll
  for (int qf = 0; qf < 2; ++qf) {
    float m = -1e30f;
#pragma unroll
    for (int kvf = 0; kvf < 16; ++kvf)
#pragma unroll
      for (int e = 0; e < 4; ++e) m = fmaxf(m, s[kvf][qf][e]);
    m = fmaxf(m, __shfl_xor(m, 16));
    m = fmaxf(m, __shfl_xor(m, 32));
    float sum = 0.f;
#pragma unroll
    for (int kvf = 0; kvf < 16; ++kvf)
#pragma unroll
      for (int e = 0; e < 4; ++e) {
        const float p = __builtin_amdgcn_exp2f(s[kvf][qf][e] - m);
        s[kvf][qf][e] = p;
        sum += p;
      }
    sum += __shfl_xor(sum, 16);
    sum += __shfl_xor(sum, 32);
    inv[qf] = 1.0f / sum;
  }
  // ---- stage V^T (64 d x 256 kv), fragment-major (overwrites K frags) ----
  __syncthreads();
  {
    const ushort* Vb = vt + (size_t)(h * 64) * 1024 + b * 256;
#pragma unroll
    for (int i = 0; i < 8; ++i) {
      const int u = i * 256 + tid;
      const int d = u >> 5, c8 = u & 31, kv0 = c8 * 8;
      const int4 dd = *(const int4*)(Vb + (size_t)d * 1024 + kv0);
      const int f = (d >> 4) * 8 + (kv0 >> 5);
      const int g0 = (kv0 >> 2) & 3, hh2 = (kv0 >> 4) & 1;
      wr_chunk(kv_lds, (f * 64 + 16 * g0 + (d & 15)) * 8 + hh2 * 4, dd);
    }
  }
  __syncthreads();
  // ---- PV (unnormalized P) ----
  float4v o[2][4];
#pragma unroll
  for (int qf = 0; qf < 2; ++qf)
#pragma unroll
    for (int nf = 0; nf < 4; ++nf) o[qf][nf] = zf;
#pragma unroll
  for (int t = 0; t < 8; ++t) {
    short8v vb[4];
#pragma unroll
    for (int nf = 0; nf < 4; ++nf)
      vb[nf] = *(const short8v*)&kv_lds[((nf * 8 + t) * 64 + lane) * 8];
#pragma unroll
    for (int qf = 0; qf < 2; ++qf) {
      short8v pa;
#pragma unroll
      for (int j = 0; j < 4; ++j) {
        pa[j]     = (short)f2bf_bits(s[2 * t][qf][j]);
        pa[4 + j] = (short)f2bf_bits(s[2 * t + 1][qf][j]);
      }
#pragma unroll
      for (int nf = 0; nf < 4; ++nf) o[qf][nf] = mfma16(pa, vb[nf], o[qf][nf]);
    }
  }
  // ---- normalize at output: row q = 16qf+4lg+reg needs inv from lane lid'=4lg+reg ----
#pragma unroll
  for (int qf = 0; qf < 2; ++qf) {
    float sc[4];
#pragma unroll
    for (int reg = 0; reg < 4; ++reg) sc[reg] = __shfl(inv[qf], 4 * lg + reg);
#pragma unroll
    for (int nf = 0; nf < 4; ++nf)
#pragma unroll
      for (int reg = 0; reg < 4; ++reg) {
        const int q = qrow0 + qf * 16 + 4 * lg + reg;
        const int c = h * 64 + nf * 16 + lid;
        attno[(size_t)(b * 4096 + q) * 512 + c] = f2bf_bits(o[qf][nf][reg] * sc[reg]);
      }
  }
}

extern "C" void kernel_launch(void* const* d_in, const int* in_sizes, int n_in,
                              void* d_out, int out_size, void* d_ws, size_t ws_size,
                              hipStream_t stream) {
  const float* x     = (const float*)d_in[0];
  const float* wq    = (const float*)d_in[1];
  const float* bq    = (const float*)d_in[2];
  const float* wk    = (const float*)d_in[3];
  const float* bk    = (const float*)d_in[4];
  const float* wv    = (const float*)d_in[5];
  const float* bv    = (const float*)d_in[6];
  const float* wsr   = (const float*)d_in[7];
  const float* bsr   = (const float*)d_in[8];
  const float* gamma = (const float*)d_in[9];
  const float* beta  = (const float*)d_in[10];
  const float* wp    = (const float*)d_in[11];
  const float* bp    = (const float*)d_in[12];
  float* out = (float*)d_out;

  char* w = (char*)d_ws;                         // ws >= 256 MB; no aliasing needed
  ushort* xbf   = (ushort*)(w);                  // 16,777,216 B
  ushort* qbf   = (ushort*)(w + 16777216);       // 16,777,216
  ushort* attno = (ushort*)(w + 33554432);       // 16,777,216
  float*  part  = (float*) (w + 50331648);       // 33,554,432 (z=16)
  ushort* wsrT  = (ushort*)(w + 83886080);       //  8,388,608
  ushort* wqT   = (ushort*)(w + 92274688);       //    524,288
  ushort* wpT   = (ushort*)(w + 92798976);       //    524,288
  ushort* wkvT  = (ushort*)(w + 93323264);       //  1,048,576
  ushort* xln   = (ushort*)(w + 94371840);       //  1,048,576
  ushort* kbf   = (ushort*)(w + 95420416);       //  1,048,576 (K)
  ushort* vt    = (ushort*)(w + 96468992);       //  1,048,576 (V^T), contiguous after kbf
  float*  bkv   = (float*) (w + 97517568);       //      4,096

  prep<<<9220, 256, 0, stream>>>(x, wq, wk, wv, wp, wsr, bk, bv,
                                 xbf, wqT, wkvT, wpT, wsrT, bkv);
  conv_bf<<<dim3(8, 4, 16), 256, 0, stream>>>(xbf, wsrT, part);
  reduce_ln<<<256, 256, 0, stream>>>(part, bsr, gamma, beta, xln);
  gemm_bf<2><<<dim3(8, 8), 256, 0, stream>>>(xln, wkvT, bkv, kbf, 1024, 1024, 512, 1.0f);
  gemm_bf<1><<<dim3(128, 4), 256, 0, stream>>>(xbf, wqT, bq, qbf, 16384, 512, 512, SCALE_Q);
  attn_bf<<<dim3(32, 32), 256, 0, stream>>>(qbf, kbf, vt, attno);
  gemm_bf<0><<<dim3(128, 4), 256, 0, stream>>>(attno, wpT, bp, out, 16384, 512, 512, 1.0f);
}

// Round 5
// 217.363 us; speedup vs baseline: 4.4437x; 1.1092x over previous
//
#include <hip/hip_runtime.h>
#include <hip/hip_bf16.h>

// SegFormer efficient attention, bf16 MFMA pipeline, round 5.
// B=4 N=4096 C=512 H=8 dh=64 SR=4 -> n_kv=256.
// prep(casts + LDS-tiled transposes, 1 launch) -> conv-GEMM(splitK16) -> reduce+LN
//   -> KV GEMM (K normal, V^T out) -> Q GEMM (0.125*log2e folded)
//   -> fused attn (swapped QK^T, exp2, deferred 1/sum) -> out proj (fp32).

#define EPSV 1e-5f
#define SCALE_Q 0.18033688011112042f   // 0.125 * log2(e)

typedef __attribute__((ext_vector_type(8))) short short8v;   // 8 bf16 = 1 MFMA operand
typedef __attribute__((ext_vector_type(4))) short short4v;
typedef __attribute__((ext_vector_type(4))) float float4v;

static __device__ __forceinline__ ushort f2bf_bits(float x) {
  __hip_bfloat16 h = __float2bfloat16(x);            // RNE; compiler can fuse cvt_pk
  return *(ushort*)&h;
}

static __device__ __forceinline__ float4v mfma16(short8v a, short8v b, float4v c) {
  return __builtin_amdgcn_mfma_f32_16x16x32_bf16(a, b, c, 0, 0, 0);
}

// write one staged 16B chunk (8 contiguous-k bf16) into fragment-major LDS.
// lane slot layout: k = 4*(lane>>4) + (j&3) + 16*(j>>2), row-within-frag = lane&15.
static __device__ __forceinline__ void wr_chunk(ushort* lds, int base, int4 v) {
  *(int2*)&lds[base]       = make_int2(v.x, v.y);
  *(int2*)&lds[base + 128] = make_int2(v.z, v.w);
}

// transpose one 32x32 fp32 tile of src[R][512] into dst[512][R] bf16, via LDS.
// read: coalesced float4/lane; write: 8 lanes cover 64B contiguous bf16.
static __device__ __forceinline__ void tile_t32(const float* __restrict__ src, int srcld,
                                                ushort* __restrict__ dst, int dstld,
                                                int kr0, int c0, int tid, float (*t)[33]) {
  {
    const int r = tid >> 3, c4 = (tid & 7) * 4;
    const float4 v = *(const float4*)&src[(size_t)(kr0 + r) * srcld + c0 + c4];
    t[r][c4 + 0] = v.x; t[r][c4 + 1] = v.y; t[r][c4 + 2] = v.z; t[r][c4 + 3] = v.w;
  }
  __syncthreads();
  {
    const int n = tid >> 3, k4 = (tid & 7) * 4;
    short4v o;
#pragma unroll
    for (int i = 0; i < 4; ++i) o[i] = (short)f2bf_bits(t[k4 + i][n]);
    *(short4v*)&dst[(size_t)(c0 + n) * dstld + kr0 + k4] = o;
  }
}

// ---------------- prep: all casts/transposes/bias in one launch ----------------
// blocks [0,4096): cast x -> xbf (8 elems/thread)
// blocks [4096,8192): wsr [8192][512] -> wsrT [512][8192], 32x32 LDS tiles
// blocks [8192,9216): wq/wk/wv/wp [512][512] -> T, 32x32 LDS tiles (256 blocks each)
// block 9216: bkv concat
__global__ __launch_bounds__(256)
void prep(const float* __restrict__ x, const float* __restrict__ wq,
          const float* __restrict__ wk, const float* __restrict__ wv,
          const float* __restrict__ wp, const float* __restrict__ wsr,
          const float* __restrict__ bk, const float* __restrict__ bv,
          ushort* __restrict__ xbf, ushort* __restrict__ wqT,
          ushort* __restrict__ wkvT, ushort* __restrict__ wpT,
          ushort* __restrict__ wsrT, float* __restrict__ bkv) {
  __shared__ float t[32][33];
  const int bid = blockIdx.x, tid = threadIdx.x;
  if (bid < 4096) {
    const int i = bid * 256 + tid;
    const float4* s4 = (const float4*)x;
    const float4 a = s4[2 * i], b = s4[2 * i + 1];
    short8v v;
    v[0] = (short)f2bf_bits(a.x); v[1] = (short)f2bf_bits(a.y);
    v[2] = (short)f2bf_bits(a.z); v[3] = (short)f2bf_bits(a.w);
    v[4] = (short)f2bf_bits(b.x); v[5] = (short)f2bf_bits(b.y);
    v[6] = (short)f2bf_bits(b.z); v[7] = (short)f2bf_bits(b.w);
    *(short8v*)&xbf[(size_t)i * 8] = v;
  } else if (bid < 8192) {
    const int tI = bid - 4096;                    // 4096 tiles: 256 row-tiles x 16 col-tiles
    const int kr0 = (tI & 255) * 32, c0 = (tI >> 8) * 32;
    tile_t32(wsr, 512, wsrT, 8192, kr0, c0, tid, t);
  } else if (bid < 9216) {
    const int wsel = (bid - 8192) >> 8;           // 256 tiles per 512x512 weight
    const int tI = (bid - 8192) & 255;
    const int kr0 = (tI & 15) * 32, c0 = (tI >> 4) * 32;
    const float* src = wsel == 0 ? wq : wsel == 1 ? wk : wsel == 2 ? wv : wp;
    ushort* dst = wsel == 0 ? wqT : wsel == 1 ? wkvT : wsel == 2 ? (wkvT + 262144) : wpT;
    tile_t32(src, 512, dst, 512, kr0, c0, tid, t);
  } else {
    const int i4 = tid * 4;                       // 1024 elems
    const float4 v = (i4 < 512) ? *(const float4*)&bk[i4] : *(const float4*)&bv[i4 - 512];
    *(float4*)&bkv[i4] = v;
  }
}

// ---------------- generic bf16 MFMA GEMM ----------------
// C[M,N] = A[M,K] @ BT[N,K]^T (+bias)*scale.  128x128 tile, BK=32, 4 waves (2x2 of 64x64).
// MODE 0: fp32 out; 1: bf16 out; 2: kv-split (col<512 -> K [row][col], col>=512 -> V^T [col-512][row]).
template<int MODE>
__global__ __launch_bounds__(256)
void gemm_bf(const ushort* __restrict__ A, const ushort* __restrict__ BT,
             const float* __restrict__ bias, void* __restrict__ outp,
             int M, int N, int K, float scale) {
  __shared__ ushort lds[8192];                          // A frags [0..4095], B frags [4096..]
  const int tid = threadIdx.x;
  const int wave = tid >> 6, lane = tid & 63;
  const int wm = wave >> 1, wn = wave & 1;
  const int bm = blockIdx.x * 128, bn = blockIdx.y * 128;
  const int lid = lane & 15, lg = lane >> 4;
  const int r0 = tid >> 2, c8 = tid & 3;
  const int g0 = 2 * (c8 & 1), h2 = c8 >> 1;
  const int c0 = c8 * 8;
  const int basew = ((r0 >> 4) * 64 + 16 * g0 + (r0 & 15)) * 8 + h2 * 4;
  float4v acc[4][4];
  const float4v zf = {0.f, 0.f, 0.f, 0.f};
#pragma unroll
  for (int mi = 0; mi < 4; ++mi)
#pragma unroll
    for (int ni = 0; ni < 4; ++ni) acc[mi][ni] = zf;
  const ushort* Ar0 = A + (size_t)(bm + r0) * K;
  const ushort* Ar1 = Ar0 + (size_t)64 * K;
  const ushort* Br0 = BT + (size_t)(bn + r0) * K;
  const ushort* Br1 = Br0 + (size_t)64 * K;
  const int NK = K >> 5;
  int koff = c0;
  int4 pa0 = *(const int4*)(Ar0 + koff), pa1 = *(const int4*)(Ar1 + koff);
  int4 pb0 = *(const int4*)(Br0 + koff), pb1 = *(const int4*)(Br1 + koff);
  for (int kb = 0; kb < NK; ++kb) {
    wr_chunk(lds, basew, pa0);
    wr_chunk(lds, basew + 2048, pa1);
    wr_chunk(lds, basew + 4096, pb0);
    wr_chunk(lds, basew + 6144, pb1);
    __syncthreads();
    if (kb + 1 < NK) {
      koff += 32;
      pa0 = *(const int4*)(Ar0 + koff); pa1 = *(const int4*)(Ar1 + koff);
      pb0 = *(const int4*)(Br0 + koff); pb1 = *(const int4*)(Br1 + koff);
    }
    short8v af[4], bfr[4];
#pragma unroll
    for (int mi = 0; mi < 4; ++mi)
      af[mi] = *(const short8v*)&lds[((wm * 4 + mi) * 64 + lane) * 8];
#pragma unroll
    for (int ni = 0; ni < 4; ++ni)
      bfr[ni] = *(const short8v*)&lds[4096 + ((wn * 4 + ni) * 64 + lane) * 8];
#pragma unroll
    for (int mi = 0; mi < 4; ++mi)
#pragma unroll
      for (int ni = 0; ni < 4; ++ni) acc[mi][ni] = mfma16(af[mi], bfr[ni], acc[mi][ni]);
    __syncthreads();
  }
  float bvv[4];
#pragma unroll
  for (int ni = 0; ni < 4; ++ni) bvv[ni] = bias[bn + wn * 64 + ni * 16 + lid];
#pragma unroll
  for (int mi = 0; mi < 4; ++mi)
#pragma unroll
    for (int ni = 0; ni < 4; ++ni) {
      const int col = bn + wn * 64 + ni * 16 + lid;
#pragma unroll
      for (int reg = 0; reg < 4; ++reg) {
        const int row = bm + wm * 64 + mi * 16 + 4 * lg + reg;
        const float v = (acc[mi][ni][reg] + bvv[ni]) * scale;
        if (MODE == 0) ((float*)outp)[(size_t)row * N + col] = v;
        else if (MODE == 1) ((ushort*)outp)[(size_t)row * N + col] = f2bf_bits(v);
        else {
          if (col < 512) ((ushort*)outp)[(size_t)row * 512 + col] = f2bf_bits(v);
          else ((ushort*)outp)[524288 + (size_t)(col - 512) * 1024 + row] = f2bf_bits(v);
        }
      }
    }
}

// ---------------- conv as gathered GEMM, split-K z=16, fp32 partials ----------------
static __device__ __forceinline__ int4 ld_patch(const ushort* xbf, int b, int oh, int ow, int kg) {
  const int ij = kg >> 9, ci = kg & 511;
  const int n = (oh * 4 + (ij >> 2)) * 64 + ow * 4 + (ij & 3);
  return *(const int4*)(xbf + ((size_t)b * 4096 + n) * 512 + ci);
}

__global__ __launch_bounds__(256)
void conv_bf(const ushort* __restrict__ xbf, const ushort* __restrict__ wsrT,
             float* __restrict__ part) {
  __shared__ ushort lds[8192];
  const int tid = threadIdx.x;
  const int wave = tid >> 6, lane = tid & 63;
  const int wm = wave >> 1, wn = wave & 1;
  const int bm = blockIdx.x * 128, bn = blockIdx.y * 128, z = blockIdx.z;
  const int lid = lane & 15, lg = lane >> 4;
  const int r0 = tid >> 2, c8 = tid & 3;
  const int g0 = 2 * (c8 & 1), h2 = c8 >> 1;
  const int c0 = c8 * 8;
  const int basew = ((r0 >> 4) * 64 + 16 * g0 + (r0 & 15)) * 8 + h2 * 4;
  const int p0 = bm + r0, p1 = p0 + 64;
  const int b0 = p0 >> 8, oh0 = (p0 & 255) >> 4, ow0 = p0 & 15;
  const int b1 = p1 >> 8, oh1 = (p1 & 255) >> 4, ow1 = p1 & 15;
  const ushort* Br0 = wsrT + (size_t)(bn + r0) * 8192;
  const ushort* Br1 = Br0 + (size_t)64 * 8192;
  float4v acc[4][4];
  const float4v zf = {0.f, 0.f, 0.f, 0.f};
#pragma unroll
  for (int mi = 0; mi < 4; ++mi)
#pragma unroll
    for (int ni = 0; ni < 4; ++ni) acc[mi][ni] = zf;
  int kg = z * 512 + c0;
  int4 pa0 = ld_patch(xbf, b0, oh0, ow0, kg);
  int4 pa1 = ld_patch(xbf, b1, oh1, ow1, kg);
  int4 pb0 = *(const int4*)(Br0 + kg);
  int4 pb1 = *(const int4*)(Br1 + kg);
  for (int kb = 0; kb < 16; ++kb) {
    wr_chunk(lds, basew, pa0);
    wr_chunk(lds, basew + 2048, pa1);
    wr_chunk(lds, basew + 4096, pb0);
    wr_chunk(lds, basew + 6144, pb1);
    __syncthreads();
    if (kb < 15) {
      kg += 32;
      pa0 = ld_patch(xbf, b0, oh0, ow0, kg);
      pa1 = ld_patch(xbf, b1, oh1, ow1, kg);
      pb0 = *(const int4*)(Br0 + kg);
      pb1 = *(const int4*)(Br1 + kg);
    }
    short8v af[4], bfr[4];
#pragma unroll
    for (int mi = 0; mi < 4; ++mi)
      af[mi] = *(const short8v*)&lds[((wm * 4 + mi) * 64 + lane) * 8];
#pragma unroll
    for (int ni = 0; ni < 4; ++ni)
      bfr[ni] = *(const short8v*)&lds[4096 + ((wn * 4 + ni) * 64 + lane) * 8];
#pragma unroll
    for (int mi = 0; mi < 4; ++mi)
#pragma unroll
      for (int ni = 0; ni < 4; ++ni) acc[mi][ni] = mfma16(af[mi], bfr[ni], acc[mi][ni]);
    __syncthreads();
  }
#pragma unroll
  for (int mi = 0; mi < 4; ++mi)
#pragma unroll
    for (int ni = 0; ni < 4; ++ni)
#pragma unroll
      for (int reg = 0; reg < 4; ++reg)
        part[(size_t)(z * 1024 + bm + wm * 64 + mi * 16 + 4 * lg + reg) * 512 +
             bn + wn * 64 + ni * 16 + lid] = acc[mi][ni][reg];
}

// ---------------- reduce conv partials + bias, LayerNorm -> bf16 ----------------
__global__ __launch_bounds__(256)
void reduce_ln(const float* __restrict__ part, const float* __restrict__ bsr,
               const float* __restrict__ gamma, const float* __restrict__ beta,
               ushort* __restrict__ xln) {
  const int wave = threadIdx.x >> 6;
  const int lane = threadIdx.x & 63;
  const int row = blockIdx.x * 4 + wave;
  const int c = lane * 8;
  float v[8];
  {
    const float4 a = *(const float4*)&bsr[c];
    const float4 b = *(const float4*)&bsr[c + 4];
    v[0] = a.x; v[1] = a.y; v[2] = a.z; v[3] = a.w;
    v[4] = b.x; v[5] = b.y; v[6] = b.z; v[7] = b.w;
  }
#pragma unroll
  for (int z = 0; z < 16; ++z) {
    const float* pr = &part[((size_t)z * 1024 + row) * 512 + c];
    const float4 a = *(const float4*)pr;
    const float4 b = *(const float4*)(pr + 4);
    v[0] += a.x; v[1] += a.y; v[2] += a.z; v[3] += a.w;
    v[4] += b.x; v[5] += b.y; v[6] += b.z; v[7] += b.w;
  }
  float sum = 0.f;
#pragma unroll
  for (int i = 0; i < 8; ++i) sum += v[i];
#pragma unroll
  for (int off = 32; off >= 1; off >>= 1) sum += __shfl_xor(sum, off);
  const float mu = sum * (1.0f / 512.0f);
  float sq = 0.f;
#pragma unroll
  for (int i = 0; i < 8; ++i) { v[i] -= mu; sq += v[i] * v[i]; }
#pragma unroll
  for (int off = 32; off >= 1; off >>= 1) sq += __shfl_xor(sq, off);
  const float rs = rsqrtf(sq * (1.0f / 512.0f) + EPSV);
  const float4 g1 = *(const float4*)&gamma[c];
  const float4 g2 = *(const float4*)&gamma[c + 4];
  const float4 e1 = *(const float4*)&beta[c];
  const float4 e2 = *(const float4*)&beta[c + 4];
  const float g[8] = {g1.x, g1.y, g1.z, g1.w, g2.x, g2.y, g2.z, g2.w};
  const float e[8] = {e1.x, e1.y, e1.z, e1.w, e2.x, e2.y, e2.z, e2.w};
  short8v ov;
#pragma unroll
  for (int i = 0; i < 8; ++i) ov[i] = (short)f2bf_bits(v[i] * rs * g[i] + e[i]);
  *(short8v*)&xln[(size_t)row * 512 + c] = ov;
}

// ---------------- fused attention ----------------
// grid (32 bh, 32 qtiles). block = 4 waves, each wave: 32 q x 256 kv.
// S^T = mfma(K, Q^T-frags): lane holds S[q=lid+16qf][kv=16kvf+4lg+reg] -> in-reg softmax
// (exp2; 1/sum deferred to output). P lane-local as PV's A operand. V^T staged frag-major.
__global__ __launch_bounds__(256)
void attn_bf(const ushort* __restrict__ qbf, const ushort* __restrict__ kbf,
             const ushort* __restrict__ vt, ushort* __restrict__ attno) {
  __shared__ ushort kv_lds[16384];                      // 32KB: K frags, then V frags
  const int bh = blockIdx.x, qt = blockIdx.y;
  const int b = bh >> 3, h = bh & 7;
  const int tid = threadIdx.x;
  const int wave = tid >> 6, lane = tid & 63;
  const int lid = lane & 15, lg = lane >> 4;
  // ---- stage K (256 kv x 64 d), fragment-major ----
  {
    const ushort* Kb = kbf + (size_t)(b * 256) * 512 + h * 64;
#pragma unroll
    for (int i = 0; i < 8; ++i) {
      const int u = i * 256 + tid;
      const int kv = u >> 3, c8 = u & 7, d0 = c8 * 8;
      const int4 d = *(const int4*)(Kb + (size_t)kv * 512 + d0);
      const int f = (kv >> 4) * 2 + (d0 >> 5);
      const int g0 = (d0 >> 2) & 3, hh2 = (d0 >> 4) & 1;
      wr_chunk(kv_lds, (f * 64 + 16 * g0 + (kv & 15)) * 8 + hh2 * 4, d);
    }
  }
  // ---- Q fragments to registers ----
  short8v qfr[2][2];
  const int qrow0 = qt * 128 + wave * 32;
#pragma unroll
  for (int qf = 0; qf < 2; ++qf)
#pragma unroll
    for (int t = 0; t < 2; ++t) {
      const size_t base = (size_t)(b * 4096 + qrow0 + qf * 16 + lid) * 512 + h * 64 + 32 * t + 4 * lg;
      const short4v lo = *(const short4v*)&qbf[base];
      const short4v hi = *(const short4v*)&qbf[base + 16];
      short8v q;
      q[0] = lo[0]; q[1] = lo[1]; q[2] = lo[2]; q[3] = lo[3];
      q[4] = hi[0]; q[5] = hi[1]; q[6] = hi[2]; q[7] = hi[3];
      qfr[qf][t] = q;
    }
  __syncthreads();
  // ---- QK^T (S^T in acc) ----
  float4v s[16][2];
  const float4v zf = {0.f, 0.f, 0.f, 0.f};
#pragma unroll
  for (int kvf = 0; kvf < 16; ++kvf) { s[kvf][0] = zf; s[kvf][1] = zf; }
#pragma unroll
  for (int kvf = 0; kvf < 16; ++kvf)
#pragma unroll
    for (int t = 0; t < 2; ++t) {
      const short8v ka = *(const short8v*)&kv_lds[((kvf * 2 + t) * 64 + lane) * 8];
      s[kvf][0] = mfma16(ka, qfr[0][t], s[kvf][0]);
      s[kvf][1] = mfma16(ka, qfr[1][t], s[kvf][1]);
    }
  // ---- softmax over kv (rows of S^T); scores are pre-scaled by log2e ----
  float inv[2];
#pragma unroll
  for (int qf = 0; qf < 2; ++qf) {
    float m = -1e30f;
#pragma unroll
    for (int kvf = 0; kvf < 16; ++kvf)
#pragma unroll
      for (int e = 0; e < 4; ++e) m = fmaxf(m, s[kvf][qf][e]);
    m = fmaxf(m, __shfl_xor(m, 16));
    m = fmaxf(m, __shfl_xor(m, 32));
    float sum = 0.f;
#pragma unroll
    for (int kvf = 0; kvf < 16; ++kvf)
#pragma unroll
      for (int e = 0; e < 4; ++e) {
        const float p = __builtin_amdgcn_exp2f(s[kvf][qf][e] - m);
        s[kvf][qf][e] = p;
        sum += p;
      }
    sum += __shfl_xor(sum, 16);
    sum += __shfl_xor(sum, 32);
    inv[qf] = 1.0f / sum;
  }
  // ---- stage V^T (64 d x 256 kv), fragment-major (overwrites K frags) ----
  __syncthreads();
  {
    const ushort* Vb = vt + (size_t)(h * 64) * 1024 + b * 256;
#pragma unroll
    for (int i = 0; i < 8; ++i) {
      const int u = i * 256 + tid;
      const int d = u >> 5, c8 = u & 31, kv0 = c8 * 8;
      const int4 dd = *(const int4*)(Vb + (size_t)d * 1024 + kv0);
      const int f = (d >> 4) * 8 + (kv0 >> 5);
      const int g0 = (kv0 >> 2) & 3, hh2 = (kv0 >> 4) & 1;
      wr_chunk(kv_lds, (f * 64 + 16 * g0 + (d & 15)) * 8 + hh2 * 4, dd);
    }
  }
  __syncthreads();
  // ---- PV (unnormalized P) ----
  float4v o[2][4];
#pragma unroll
  for (int qf = 0; qf < 2; ++qf)
#pragma unroll
    for (int nf = 0; nf < 4; ++nf) o[qf][nf] = zf;
#pragma unroll
  for (int t = 0; t < 8; ++t) {
    short8v vb[4];
#pragma unroll
    for (int nf = 0; nf < 4; ++nf)
      vb[nf] = *(const short8v*)&kv_lds[((nf * 8 + t) * 64 + lane) * 8];
#pragma unroll
    for (int qf = 0; qf < 2; ++qf) {
      short8v pa;
#pragma unroll
      for (int j = 0; j < 4; ++j) {
        pa[j]     = (short)f2bf_bits(s[2 * t][qf][j]);
        pa[4 + j] = (short)f2bf_bits(s[2 * t + 1][qf][j]);
      }
#pragma unroll
      for (int nf = 0; nf < 4; ++nf) o[qf][nf] = mfma16(pa, vb[nf], o[qf][nf]);
    }
  }
  // ---- normalize at output: row q = 16qf+4lg+reg needs inv from lane lid'=4lg+reg ----
#pragma unroll
  for (int qf = 0; qf < 2; ++qf) {
    float sc[4];
#pragma unroll
    for (int reg = 0; reg < 4; ++reg) sc[reg] = __shfl(inv[qf], 4 * lg + reg);
#pragma unroll
    for (int nf = 0; nf < 4; ++nf)
#pragma unroll
      for (int reg = 0; reg < 4; ++reg) {
        const int q = qrow0 + qf * 16 + 4 * lg + reg;
        const int c = h * 64 + nf * 16 + lid;
        attno[(size_t)(b * 4096 + q) * 512 + c] = f2bf_bits(o[qf][nf][reg] * sc[reg]);
      }
  }
}

extern "C" void kernel_launch(void* const* d_in, const int* in_sizes, int n_in,
                              void* d_out, int out_size, void* d_ws, size_t ws_size,
                              hipStream_t stream) {
  const float* x     = (const float*)d_in[0];
  const float* wq    = (const float*)d_in[1];
  const float* bq    = (const float*)d_in[2];
  const float* wk    = (const float*)d_in[3];
  const float* bk    = (const float*)d_in[4];
  const float* wv    = (const float*)d_in[5];
  const float* bv    = (const float*)d_in[6];
  const float* wsr   = (const float*)d_in[7];
  const float* bsr   = (const float*)d_in[8];
  const float* gamma = (const float*)d_in[9];
  const float* beta  = (const float*)d_in[10];
  const float* wp    = (const float*)d_in[11];
  const float* bp    = (const float*)d_in[12];
  float* out = (float*)d_out;

  char* w = (char*)d_ws;                         // ws >= 256 MB; no aliasing needed
  ushort* xbf   = (ushort*)(w);                  // 16,777,216 B
  ushort* qbf   = (ushort*)(w + 16777216);       // 16,777,216
  ushort* attno = (ushort*)(w + 33554432);       // 16,777,216
  float*  part  = (float*) (w + 50331648);       // 33,554,432 (z=16)
  ushort* wsrT  = (ushort*)(w + 83886080);       //  8,388,608
  ushort* wqT   = (ushort*)(w + 92274688);       //    524,288
  ushort* wpT   = (ushort*)(w + 92798976);       //    524,288
  ushort* wkvT  = (ushort*)(w + 93323264);       //  1,048,576
  ushort* xln   = (ushort*)(w + 94371840);       //  1,048,576
  ushort* kbf   = (ushort*)(w + 95420416);       //  1,048,576 (K)
  ushort* vt    = (ushort*)(w + 96468992);       //  1,048,576 (V^T), contiguous after kbf
  float*  bkv   = (float*) (w + 97517568);       //      4,096

  prep<<<9217, 256, 0, stream>>>(x, wq, wk, wv, wp, wsr, bk, bv,
                                 xbf, wqT, wkvT, wpT, wsrT, bkv);
  conv_bf<<<dim3(8, 4, 16), 256, 0, stream>>>(xbf, wsrT, part);
  reduce_ln<<<256, 256, 0, stream>>>(part, bsr, gamma, beta, xln);
  gemm_bf<2><<<dim3(8, 8), 256, 0, stream>>>(xln, wkvT, bkv, kbf, 1024, 1024, 512, 1.0f);
  gemm_bf<1><<<dim3(128, 4), 256, 0, stream>>>(xbf, wqT, bq, qbf, 16384, 512, 512, SCALE_Q);
  attn_bf<<<dim3(32, 32), 256, 0, stream>>>(qbf, kbf, vt, attno);
  gemm_bf<0><<<dim3(128, 4), 256, 0, stream>>>(attno, wpT, bp, out, 16384, 512, 512, 1.0f);
}